// Round 1
// baseline (1002.439 us; speedup 1.0000x reference)
//
#include <hip/hip_runtime.h>

typedef float f32x4  __attribute__((ext_vector_type(4)));
typedef float f32x16 __attribute__((ext_vector_type(16)));
typedef int   i32x4  __attribute__((ext_vector_type(4)));
typedef int   i32x8  __attribute__((ext_vector_type(8)));

#define AS1 __attribute__((address_space(1)))
#define AS3 __attribute__((address_space(3)))

// ---------------------------------------------------------------------------
// Kernel 1 (R1, proven): per-token quant of x -> fp8 e4m3 + scale
// ---------------------------------------------------------------------------
__global__ __launch_bounds__(256) void quant_x_fp8_kernel(
    const float* __restrict__ x, unsigned char* __restrict__ x8,
    float* __restrict__ xs, int K) {
  int m = blockIdx.x;
  int t = threadIdx.x;
  const f32x4* src = (const f32x4*)(x + (size_t)m * K + t * 16);
  f32x4 v[4];
  float am = 0.0f;
#pragma unroll
  for (int i = 0; i < 4; ++i) {
    v[i] = src[i];
#pragma unroll
    for (int j = 0; j < 4; ++j) am = fmaxf(am, __builtin_fabsf(v[i][j]));
  }
#pragma unroll
  for (int off = 32; off >= 1; off >>= 1)
    am = fmaxf(am, __shfl_xor(am, off, 64));
  __shared__ float red[4];
  int wv = t >> 6, lane = t & 63;
  if (lane == 0) red[wv] = am;
  __syncthreads();
  am = fmaxf(fmaxf(red[0], red[1]), fmaxf(red[2], red[3]));
  am = fmaxf(am, 1e-12f);
  float sc = am / 448.0f;
  if (t == 0) xs[m] = sc;
  i32x4 out;
#pragma unroll
  for (int i = 0; i < 4; ++i) {
    float q0 = v[i][0] / sc, q1 = v[i][1] / sc;
    float q2 = v[i][2] / sc, q3 = v[i][3] / sc;
    int p = __builtin_amdgcn_cvt_pk_fp8_f32(q0, q1, 0, false);
    p = __builtin_amdgcn_cvt_pk_fp8_f32(q2, q3, p, true);
    out[i] = p;
  }
  *(i32x4*)(x8 + (size_t)m * K + t * 16) = out;
}

// ---------------------------------------------------------------------------
// Kernel 2 (R1, proven): weight f32 (fp8-representable) -> fp8 bytes
// ---------------------------------------------------------------------------
__global__ __launch_bounds__(256) void quant_w_fp8_kernel(
    const float* __restrict__ w, unsigned char* __restrict__ w8) {
  size_t idx = (size_t)blockIdx.x * 256 + threadIdx.x;
  const f32x4* src = (const f32x4*)w + idx * 4;
  i32x4 out;
#pragma unroll
  for (int i = 0; i < 4; ++i) {
    f32x4 v = src[i];
    int p = __builtin_amdgcn_cvt_pk_fp8_f32(v[0], v[1], 0, false);
    p = __builtin_amdgcn_cvt_pk_fp8_f32(v[2], v[3], p, true);
    out[i] = p;
  }
  ((i32x4*)w8)[idx] = out;
}

// ---------------------------------------------------------------------------
// Kernel 3: MX-fp8 GEMM. R13: LDS-BW rebalance.
// Block tile 256(M)x256(N), K-tile 128 (= scale block). 8 waves 2(wr)x4(wc);
// per-wave output 128x64 = 4mj x 2nj of 32x32 frags -> acc 128 VGPR.
// Rationale: old 64x64 wave tile read (64+64)rows*128B from LDS per K-tile
// per wave vs 8 MFMA -> LDS ~1.6x MFMA time (MfmaUtil 32%, conflicts =
// 4cy/b128 intrinsic cost). 128x64 cuts LDS bytes/FLOP by 33% -> LDS ~= MFMA.
// LDS: 2 bufs x 64KB {A: 256 rows x 128B = 32KB @0, B: 32KB @+32768};
// buf0 @0, buf1 @65536 (128KB total, 1 block/CU, 8 waves).
// Swizzle (validated R11): 16B slot s at row r stored s^(r&7); inverse
// pre-applied on global source (rule #21).
// 8 phases / 2 K-tiles, one mj per phase in order {0,2,1,3} so A sweeps
// {0,2} (rows 0-63,128-191) are last-read at P2 and {1,3} at P3.
// Stage slots (2 gloads/thread each), all >=1 closing-barrier after the
// region's last consuming read:
//   P0: A(T+1)sw13->buf1 (last read prev P7) | P1: B(T+2)01->buf0 (P0)
//   P2: B(T+2)23->buf0 (P0)                  | P3: A(T+2)sw02->buf0 (P2)
//   P4: A(T+2)sw13->buf0 (P3)                | P5: B(T+3)01->buf1 (P4)
//   P6: B(T+3)23->buf1 (P4)                  | P7: A(T+3)sw02->buf1 (P6)
// Waits (counted, in-order vmcnt): end-P0 vmcnt(8) -> prev-P4 A(T)13 done
// before P1 reads; end-P3 vmcnt(6) -> P0's A(T+1)13 done before P5 (and
// prev-P7 A(T+1)02 before P4); end-P7 vmcnt(8) -> P1..P3 (B,A02 of T+2)
// done before next P0. Every prefetch gets 3-4 phases of cover (old
// schedule: 1.5 phases at vmcnt(2)).
// ---------------------------------------------------------------------------
__global__ __launch_bounds__(512, 2) void gemm_mxfp8_kernel(
    const unsigned char* __restrict__ A8,   // [M][K] fp8
    const unsigned char* __restrict__ W8,   // [N][K] fp8
    const float* __restrict__ xs,           // [M]
    const float* __restrict__ wsinv,        // [N/128][K/128]
    float* __restrict__ Y,                  // [M][N] f32
    int M, int N, int K) {
  const int KB = K >> 7;  // K/128 tiles (32)

  int bid = blockIdx.x, nwg = gridDim.x;
  int wg = (bid & 7) * (nwg >> 3) + (bid >> 3);
  int mt = M >> 8;                  // 16
  int bm = wg & (mt - 1);
  int bn = wg / mt;                 // 0..31
  int m0 = bm << 8, n0 = bn << 8;   // 256 x 256 tile

  __shared__ __align__(16) char lds[131072];

  const int tid = threadIdx.x, wv = tid >> 6, lane = tid & 63;
  const int wr = wv >> 2, wc = wv & 3;          // 2 x 4 wave grid
  const int l31 = lane & 31, hi2 = lane >> 5;
  const int salt = l31 & 7;

  // fragment addressing (within a buf: A at 0, B at +32768)
  const int aRow = (wr * 128 + l31) * 128;
  const int bRow = 32768 + (wc * 64 + l31) * 128;
  const int sL0 = ((hi2 * 2 + 0) ^ salt) << 4;       // ks=0, k-low 16B
  const int sH0 = ((hi2 * 2 + 1) ^ salt) << 4;       // ks=0, k-high
  const int sL1 = ((4 + hi2 * 2 + 0) ^ salt) << 4;   // ks=1
  const int sH1 = ((4 + hi2 * 2 + 1) ^ salt) << 4;

  // staging: dest = region + sweep*8192 + tid*16 (linear, 64 rows/sweep);
  // source row = sweep*64 + (tid>>3); col pre-swizzled (involution).
  const int stgD = tid << 4;
  const int rIdx = tid >> 3;
  const int cSrc = ((tid & 7) ^ ((tid >> 3) & 7)) << 4;
  const size_t rowB = (size_t)K;  // fp8: 1 byte/elem
  const size_t g64 = 64 * rowB;
  const char* pA = (const char*)A8 + (size_t)(m0 + rIdx) * rowB + cSrc;
  const char* pB = (const char*)W8 + (size_t)(n0 + rIdx) * rowB + cSrc;

  // scale row: N-tile 256 spans 2 scale rows; wc 0,1 -> row bn*2, wc 2,3 -> +1
  const float* wsv = wsinv + (size_t)(bn * 2 + (wc >> 1)) * KB;

  f32x16 acc[4][2];
#pragma unroll
  for (int i = 0; i < 4; ++i)
#pragma unroll
    for (int j = 0; j < 2; ++j) acc[i][j] = (f32x16)0.0f;

  i32x8 af[2], bf[2][2];

#define GL(SRC, DST)                                                           \
  __builtin_amdgcn_global_load_lds((const AS1 void*)(SRC), (AS3 void*)(DST),   \
                                   16, 0, 0)
// A sweeps 0,2 (rows 0-63 / 128-191)
#define STG_A02(COND, BASE, TT)                                                \
  if (COND) {                                                                  \
    const char* s_ = pA + (size_t)(TT)*128;                                    \
    char* d_ = lds + (BASE) + stgD;                                            \
    GL(s_, d_);                                                                \
    GL(s_ + 2 * g64, d_ + 16384);                                              \
  }
// A sweeps 1,3 (rows 64-127 / 192-255)
#define STG_A13(COND, BASE, TT)                                                \
  if (COND) {                                                                  \
    const char* s_ = pA + (size_t)(TT)*128 + g64;                              \
    char* d_ = lds + (BASE) + 8192 + stgD;                                     \
    GL(s_, d_);                                                                \
    GL(s_ + 2 * g64, d_ + 16384);                                              \
  }
// B sweeps 0,1 (rows 0-127)
#define STG_B01(COND, BASE, TT)                                                \
  if (COND) {                                                                  \
    const char* s_ = pB + (size_t)(TT)*128;                                    \
    char* d_ = lds + (BASE) + 32768 + stgD;                                    \
    GL(s_, d_);                                                                \
    GL(s_ + g64, d_ + 8192);                                                   \
  }
// B sweeps 2,3 (rows 128-255)
#define STG_B23(COND, BASE, TT)                                                \
  if (COND) {                                                                  \
    const char* s_ = pB + (size_t)(TT)*128 + 2 * g64;                          \
    char* d_ = lds + (BASE) + 32768 + 16384 + stgD;                            \
    GL(s_, d_);                                                                \
    GL(s_ + g64, d_ + 8192);                                                   \
  }

// A frags for one mj (both ksteps): 4 ds_read_b128 -> af[2]
#define RD_A(BUFB, MJ)                                                         \
  {                                                                            \
    const char* p_ = lds + (BUFB) + aRow + (MJ)*4096;                          \
    i32x4 lo0 = *(const i32x4*)(p_ + sL0);                                     \
    i32x4 hi0 = *(const i32x4*)(p_ + sH0);                                     \
    i32x4 lo1 = *(const i32x4*)(p_ + sL1);                                     \
    i32x4 hi1 = *(const i32x4*)(p_ + sH1);                                     \
    af[0] = __builtin_shufflevector(lo0, hi0, 0, 1, 2, 3, 4, 5, 6, 7);         \
    af[1] = __builtin_shufflevector(lo1, hi1, 0, 1, 2, 3, 4, 5, 6, 7);         \
  }
// all B frags (nj 0..1 x ks 0..1): 8 ds_read_b128
#define RD_B(BUFB)                                                             \
  _Pragma("unroll") for (int nj = 0; nj < 2; ++nj) {                           \
    const char* p_ = lds + (BUFB) + bRow + nj * 4096;                          \
    i32x4 lo0 = *(const i32x4*)(p_ + sL0);                                     \
    i32x4 hi0 = *(const i32x4*)(p_ + sH0);                                     \
    i32x4 lo1 = *(const i32x4*)(p_ + sL1);                                     \
    i32x4 hi1 = *(const i32x4*)(p_ + sH1);                                     \
    bf[nj][0] = __builtin_shufflevector(lo0, hi0, 0, 1, 2, 3, 4, 5, 6, 7);     \
    bf[nj][1] = __builtin_shufflevector(lo1, hi1, 0, 1, 2, 3, 4, 5, 6, 7);     \
  }

// 4 MFMA (2 nj x ks-chain) + fold by SV into acc[MJ][*]
#define MMF(MJ, SV)                                                            \
  _Pragma("unroll") for (int nj = 0; nj < 2; ++nj) {                           \
    f32x16 t_ = __builtin_amdgcn_mfma_scale_f32_32x32x64_f8f6f4(               \
        af[0], bf[nj][0], (f32x16)0.0f, 0, 0, 0, 0x7f7f7f7f, 0, 0x7f7f7f7f);   \
    t_ = __builtin_amdgcn_mfma_scale_f32_32x32x64_f8f6f4(                      \
        af[1], bf[nj][1], t_, 0, 0, 0, 0x7f7f7f7f, 0, 0x7f7f7f7f);             \
    _Pragma("unroll") for (int q = 0; q < 16; ++q)                             \
        acc[MJ][nj][q] = __builtin_fmaf(SV, t_[q], acc[MJ][nj][q]);            \
  }

#define PH(RD, ST, MM_)                                                        \
  {                                                                            \
    RD;                                                                        \
    ST;                                                                        \
    __builtin_amdgcn_s_barrier();                                              \
    __builtin_amdgcn_s_setprio(1);                                             \
    MM_;                                                                       \
    __builtin_amdgcn_s_setprio(0);                                             \
    __builtin_amdgcn_s_barrier();                                              \
  }
#define PHW(RD, ST, MM_, VM)                                                   \
  {                                                                            \
    RD;                                                                        \
    ST;                                                                        \
    __builtin_amdgcn_s_barrier();                                              \
    __builtin_amdgcn_s_setprio(1);                                             \
    MM_;                                                                       \
    __builtin_amdgcn_s_setprio(0);                                             \
    asm volatile("s_waitcnt " VM ::: "memory");                                \
    __builtin_amdgcn_s_barrier();                                              \
  }

  // prologue: mirror steady invariant. Issue (2 gloads each):
  // B(0)01 B(0)23 A(0)02 A(0)13 B(1)01 B(1)23 A(1)02 = 14 gloads;
  // vmcnt(8) completes B(0)+A(0)02 (needed at P0), leaves
  // {A(0)13, B(1)01, B(1)23, A(1)02} = 8 outstanding = steady entry state.
  STG_B01(true, 0, 0);
  STG_B23(true, 0, 0);
  STG_A02(true, 0, 0);
  STG_A13(true, 0, 0);
  STG_B01(true, 65536, 1);
  STG_B23(true, 65536, 1);
  STG_A02(true, 65536, 1);
  asm volatile("s_waitcnt vmcnt(8)" ::: "memory");
  __builtin_amdgcn_s_barrier();

#define ITER(T, G, V0, V3, V7)                                                 \
  {                                                                            \
    float s0_ = wsv[(T)];                                                      \
    float s1_ = wsv[(T) + 1];                                                  \
    PHW(RD_B(0); RD_A(0, 0), STG_A13(true, 65536, (T) + 1), MMF(0, s0_), V0)   \
    PH(RD_A(0, 2), STG_B01(G, 0, (T) + 2), MMF(2, s0_))                        \
    PH(RD_A(0, 1), STG_B23(G, 0, (T) + 2), MMF(1, s0_))                        \
    PHW(RD_A(0, 3), STG_A02(G, 0, (T) + 2), MMF(3, s0_), V3)                   \
    PH(RD_B(65536); RD_A(65536, 0), STG_A13(G, 0, (T) + 2), MMF(0, s1_))       \
    PH(RD_A(65536, 2), STG_B01(G, 65536, (T) + 3), MMF(2, s1_))                \
    PH(RD_A(65536, 1), STG_B23(G, 65536, (T) + 3), MMF(1, s1_))                \
    PHW(RD_A(65536, 3), STG_A02(G, 65536, (T) + 3), MMF(3, s1_), V7)           \
  }

  for (int t = 0; t < KB - 2; t += 2) {
    ITER(t, true, "vmcnt(8)", "vmcnt(6)", "vmcnt(8)");
  }
  // tail (tiles KB-2, KB-1): only A(KB-1)sw13 staged at P0; drain by P3.
  ITER(KB - 2, false, "vmcnt(8)", "vmcnt(0)", "vmcnt(0)");

#undef ITER
#undef PHW
#undef PH
#undef MMF
#undef RD_B
#undef RD_A
#undef STG_B23
#undef STG_B01
#undef STG_A13
#undef STG_A02
#undef GL

  // epilogue (validated C/D mapping): col=l31, row=q*8+hi2*4+j
#pragma unroll
  for (int mj = 0; mj < 4; ++mj)
#pragma unroll
    for (int nj = 0; nj < 2; ++nj) {
      int col = n0 + wc * 64 + nj * 32 + l31;
#pragma unroll
      for (int q = 0; q < 4; ++q) {
        int row0 = m0 + wr * 128 + mj * 32 + q * 8 + hi2 * 4;
        f32x4 sv = *(const f32x4*)(xs + row0);
#pragma unroll
        for (int j = 0; j < 4; ++j)
          Y[(size_t)(row0 + j) * N + col] = acc[mj][nj][q * 4 + j] * sv[j];
      }
    }
}

// ---------------------------------------------------------------------------
extern "C" void kernel_launch(void* const* d_in, const int* in_sizes, int n_in,
                              void* d_out, int out_size, void* d_ws, size_t ws_size,
                              hipStream_t stream) {
  const float* x     = (const float*)d_in[0];   // [B,S,K] f32
  const float* w     = (const float*)d_in[1];   // [N,K] f32 (fp8-representable)
  const float* wsinv = (const float*)d_in[2];   // [N/128,K/128] f32
  float* y = (float*)d_out;

  const int K = 4096;
  const int M = in_sizes[0] / K;   // 4096
  const int N = in_sizes[1] / K;   // 8192

  unsigned char* x8 = (unsigned char*)d_ws;                       // M*K
  float* xs = (float*)((char*)d_ws + (size_t)M * K);              // M floats
  unsigned char* w8 =
      (unsigned char*)d_ws + (size_t)M * K + (size_t)M * 4;       // N*K

  quant_x_fp8_kernel<<<M, 256, 0, stream>>>(x, x8, xs, K);
  quant_w_fp8_kernel<<<(int)(((size_t)N * K / 16 + 255) / 256), 256, 0,
                       stream>>>(w, w8);

  dim3 grid((M / 256) * (N / 256));  // 512
  gemm_mxfp8_kernel<<<grid, 512, 0, stream>>>(x8, w8, xs, wsinv, y, M, N, K);
}